// Round 9
// baseline (132.907 us; speedup 1.0000x reference)
//
#include <hip/hip_runtime.h>

#define NB 8192   // batch
#define NC 1024   // controller width (K)
#define NM 4096   // memory size (N)
#define NCH 16    // NM / 256 (256-col chunks per row)

typedef __attribute__((ext_vector_type(8))) short bf16x8;
typedef __attribute__((ext_vector_type(4))) float f32x4;

__device__ __forceinline__ unsigned short f2bf(float x) {
  unsigned int u = __float_as_uint(x);
  u += 0x7FFFu + ((u >> 16) & 1u);
  return (unsigned short)(u >> 16);
}
__device__ __forceinline__ unsigned int pk2(float a, float b) {
  return (unsigned int)f2bf(a) | ((unsigned int)f2bf(b) << 16);
}

__device__ __forceinline__ void gload_lds16(const void* g, void* l) {
  __builtin_amdgcn_global_load_lds(
      (const __attribute__((address_space(1))) unsigned int*)g,
      (__attribute__((address_space(3))) unsigned int*)l, 16, 0, 0);
}

#define DSR(dst, addr, IMM) \
  asm volatile("ds_read_b128 %0, %1 offset:" IMM : "=v"(dst) : "v"(addr))

// ------- Kernel 0: fused prep: W [K,N] f32 -> Wt [N,K] bf16  AND co -> bf16 ----
__global__ __launch_bounds__(256) void prep_k(const float* __restrict__ W,
                                              unsigned short* __restrict__ Wt,
                                              const float* __restrict__ coin,
                                              unsigned short* __restrict__ Abf) {
  __shared__ float tile[64][65];
  const int bid = blockIdx.x;
  const int t = threadIdx.x;
  if (bid < 1024) {  // ---- convW part ----
    const int n0 = (bid & 63) * 64, k0 = (bid >> 6) * 64;
    const int r = t >> 2, q = t & 3;
    const float4* src = reinterpret_cast<const float4*>(W + (size_t)(k0 + r) * NM + n0 + q * 16);
    float4 x0 = src[0], x1 = src[1], x2 = src[2], x3 = src[3];
    float* tr = &tile[r][q * 16];
    tr[0]=x0.x; tr[1]=x0.y; tr[2]=x0.z;  tr[3]=x0.w;
    tr[4]=x1.x; tr[5]=x1.y; tr[6]=x1.z;  tr[7]=x1.w;
    tr[8]=x2.x; tr[9]=x2.y; tr[10]=x2.z; tr[11]=x2.w;
    tr[12]=x3.x; tr[13]=x3.y; tr[14]=x3.z; tr[15]=x3.w;
    __syncthreads();
    unsigned int pk[8];
#pragma unroll
    for (int i = 0; i < 8; ++i)
      pk[i] = pk2(tile[q * 16 + 2 * i][r], tile[q * 16 + 2 * i + 1][r]);
    int4* dst = reinterpret_cast<int4*>(Wt + (size_t)(n0 + r) * NC + k0 + q * 16);
    dst[0] = make_int4((int)pk[0], (int)pk[1], (int)pk[2], (int)pk[3]);
    dst[1] = make_int4((int)pk[4], (int)pk[5], (int)pk[6], (int)pk[7]);
  } else {  // ---- convA part ----
    const size_t i = ((size_t)(bid - 1024) * 256 + t) * 8;
    const float4* s = reinterpret_cast<const float4*>(coin + i);
    float4 x0 = s[0], x1 = s[1];
    int4 o = make_int4((int)pk2(x0.x, x0.y), (int)pk2(x0.z, x0.w),
                       (int)pk2(x1.x, x1.y), (int)pk2(x1.z, x1.w));
    *reinterpret_cast<int4*>(Abf + i) = o;
  }
}

// ------- Kernel 2: 256x256-tile 8-phase bf16 MFMA GEMM (T1+T2+T3+T4+T5)
//         + memry L2-prefetch in drain phases + two-phase fused epilogue -------
__global__ __launch_bounds__(512) void gemm_fused(
    const unsigned short* __restrict__ Abf, const float* __restrict__ memry,
    const unsigned short* __restrict__ Wt, const float* __restrict__ bvec,
    float* __restrict__ pdotg, float* __restrict__ pesqg,
    float* __restrict__ pmsqg, float* __restrict__ pmsg) {
  __shared__ __align__(16) unsigned short LDS[2][4][8192];  // 128 KiB
  // T1: bijective XCD swizzle (512 blocks, 8 XCDs, 64 blocks/XCD).
  // Each XCD runs all 32 bm for one bn per round -> its B panel is L2-resident.
  const int didx = blockIdx.y * 32 + blockIdx.x;   // HW dispatch order (x fastest)
  const int nl = (didx & 7) * 64 + (didx >> 3);
  const int bm = nl & 31, bn = nl >> 5;
  const int row0 = bm * 256, col0 = bn * 256;
  const int t = threadIdx.x;
  const int wid = t >> 6, lane = t & 63;
  const int wr = wid >> 2, wc = wid & 3;          // 2 x 4 waves
  const int l15 = lane & 15, lg = lane >> 4;
  const int ga8 = (lg ^ ((l15 >> 1) & 3)) * 8;    // swizzled k-granule (halfwords)

  f32x4 acc[8][4];
#pragma unroll
  for (int mi = 0; mi < 8; ++mi)
#pragma unroll
    for (int ni = 0; ni < 4; ++ni) acc[mi][ni] = (f32x4){0.f, 0.f, 0.f, 0.f};

  // 32-bit LDS byte offsets for inline-asm ds_read.
  // Layout byte offset: SL*65536 + TY*16384 + row*64 + ga8*2; B types at +32768.
  const unsigned ldsbase =
      (unsigned)(uintptr_t)(__attribute__((address_space(3))) void*)&LDS[0][0][0];
  const unsigned abase = ldsbase + ((wr * 128 + l15) * 32 + ga8) * 2;
  const unsigned bbase = ldsbase + 32768 + ((wc * 64 + l15) * 32 + ga8) * 2;

  // staging source (pre-swizzled column granule; same for row and row+128)
  const int srow0 = t >> 2;
  const int sk8 = ((t & 3) ^ ((srow0 >> 1) & 3)) * 8;
  const unsigned short* gA = Abf + (size_t)(row0 + srow0) * NC + sk8;
  const unsigned short* gB = Wt + (size_t)(col0 + srow0) * NC + sk8;

#define STG(SL, TY, KT)                                                      \
  {                                                                          \
    const unsigned short* s0 = ((TY) <= 1 ? gA : gB) + (KT) * 64 + ((TY)&1) * 32; \
    gload_lds16(s0, &LDS[SL][TY][t * 8]);                                    \
    gload_lds16(s0 + (size_t)128 * NC, &LDS[SL][TY][t * 8 + 4096]);          \
  }
// L2 prefetch of this block's memry tile: 1 dword per 128-B line,
// 4 touches/thread cover 256x256 f32. Keep-alive asm prevents DCE (rule #17).
#define PREF(i)                                                              \
  {                                                                          \
    const int c = t + (i)*512;                                               \
    float pv = memry[(size_t)(row0 + (c >> 3)) * NM + col0 + (c & 7) * 32];  \
    asm volatile("" ::"v"(pv));                                              \
  }
#define NOSTG
#define VM6 asm volatile("s_waitcnt vmcnt(6)" ::: "memory")
#define VM0 asm volatile("s_waitcnt vmcnt(0)" ::: "memory")
#define NOVM

#define PH(SL, S, MH, RDB, STAGE, VM)                                        \
  {                                                                          \
    if (RDB) {                                                               \
      const unsigned ba = bbase + (SL)*65536 + (S)*16384;                    \
      DSR(b[0], ba, "0");    DSR(b[1], ba, "1024");                          \
      DSR(b[2], ba, "2048"); DSR(b[3], ba, "3072");                          \
    }                                                                        \
    const unsigned aa = abase + (SL)*65536 + (S)*16384 + (MH)*4096;          \
    DSR(a[0], aa, "0");    DSR(a[1], aa, "1024");                            \
    DSR(a[2], aa, "2048"); DSR(a[3], aa, "3072");                            \
    STAGE;                                                                   \
    VM;                                                                      \
    __builtin_amdgcn_s_barrier();                                            \
    asm volatile("s_waitcnt lgkmcnt(0)" ::: "memory");                       \
    __builtin_amdgcn_sched_barrier(0);                                       \
    __builtin_amdgcn_s_setprio(1);                                           \
    _Pragma("unroll") for (int mi = 0; mi < 4; ++mi)                         \
        _Pragma("unroll") for (int ni = 0; ni < 4; ++ni)                     \
            acc[(MH)*4 + mi][ni] = __builtin_amdgcn_mfma_f32_16x16x32_bf16(  \
                a[mi], b[ni], acc[(MH)*4 + mi][ni], 0, 0, 0);                \
    __builtin_amdgcn_s_setprio(0);                                           \
    __builtin_amdgcn_s_barrier();                                            \
    __builtin_amdgcn_sched_barrier(0);                                       \
  }

  // ---- prologue: K-tile 0 fully + K-tile 1 minus Ak1 (vmcnt(6) -> slot0 landed)
  STG(0, 2, 0); STG(0, 0, 0); STG(0, 3, 0); STG(0, 1, 0);
  STG(1, 2, 1); STG(1, 0, 1); STG(1, 3, 1);
  VM6;
  __builtin_amdgcn_s_barrier();
  __builtin_amdgcn_sched_barrier(0);

  bf16x8 a[4], b[4];
  // ---- main loop: 7 iterations x 2 K-tiles (K-tiles 0..13 computed here)
  for (int it = 0; it < 7; ++it) {
    const int c1 = 2 * it + 1, c2 = 2 * it + 2, c3 = 2 * it + 3;
    PH(0, 0, 0, true,  STG(1, 1, c1), NOVM);  // ph1
    PH(0, 0, 1, false, STG(0, 2, c2), NOVM);  // ph2
    PH(0, 1, 0, true,  STG(0, 0, c2), NOVM);  // ph3
    PH(0, 1, 1, false, STG(0, 3, c2), VM6);   // ph4
    PH(1, 0, 0, true,  STG(0, 1, c2), NOVM);  // ph5
    PH(1, 0, 1, false, STG(1, 2, c3), NOVM);  // ph6
    PH(1, 1, 0, true,  STG(1, 0, c3), NOVM);  // ph7
    PH(1, 1, 1, false, STG(1, 3, c3), VM6);   // ph8
  }
  // ---- final iteration (K-tiles 14, 15); drain phases carry memry prefetch
  PH(0, 0, 0, true,  STG(1, 1, 15), NOVM);
  PH(0, 0, 1, false, NOSTG, NOVM);
  PH(0, 1, 0, true,  NOSTG, NOVM);
  PH(0, 1, 1, false, NOSTG, VM0);
  PH(1, 0, 0, true,  PREF(0), NOVM);
  PH(1, 0, 1, false, PREF(1), NOVM);
  PH(1, 1, 0, true,  PREF(2), NOVM);
  PH(1, 1, 1, false, PREF(3), NOVM);
#undef PH
#undef STG
#undef PREF

  // ---- E1: e = exp(z + b) -> bf16 into LDS [256][256], col-XOR on (rl>>2)&3
  //      so the 4 lg-rows of a write hit different bank groups ----
  unsigned short (*e_lds)[256] = reinterpret_cast<unsigned short(*)[256]>(&LDS[0][0][0]);
  float bv[4];
#pragma unroll
  for (int ni = 0; ni < 4; ++ni) bv[ni] = bvec[col0 + wc * 64 + ni * 16 + l15];
#pragma unroll
  for (int mi = 0; mi < 8; ++mi)
#pragma unroll
    for (int ni = 0; ni < 4; ++ni)
#pragma unroll
      for (int j = 0; j < 4; ++j) {
        const int rl = wr * 128 + mi * 16 + 4 * lg + j;
        const int cl = wc * 64 + ni * 16 + l15;
        e_lds[rl][cl ^ (((rl >> 2) & 3) << 4)] = f2bf(__expf(acc[mi][ni][j] + bv[ni]));
      }
  __syncthreads();

  // ---- E2: coalesced fused pass (reads L2-prefetched memry) ----
  {
    const int halfl = lane >> 5, l31 = lane & 31;
    const int rbase = wid * 32;  // each wave owns 32 consecutive rows
#pragma unroll 8
    for (int i = 0; i < 16; ++i) {
      const int rl = rbase + 2 * i + halfl;
      const float4* mp = reinterpret_cast<const float4*>(
          memry + (size_t)(row0 + rl) * NM + col0 + l31 * 8);
      float4 m0 = mp[0], m1 = mp[1];
      bf16x8 ev = *reinterpret_cast<const bf16x8*>(
          &e_lds[rl][(l31 * 8) ^ (((rl >> 2) & 3) << 4)]);
      float mv[8] = {m0.x, m0.y, m0.z, m0.w, m1.x, m1.y, m1.z, m1.w};
      float pd = 0.f, pe = 0.f, pq = 0.f, pm = 0.f;
#pragma unroll
      for (int k = 0; k < 8; ++k) {
        float e = __uint_as_float(((unsigned int)(unsigned short)ev[k]) << 16);
        pd += e * mv[k]; pe += e * e; pq += mv[k] * mv[k]; pm += mv[k];
      }
#pragma unroll
      for (int s = 1; s < 32; s <<= 1) {
        pd += __shfl_xor(pd, s); pe += __shfl_xor(pe, s);
        pq += __shfl_xor(pq, s); pm += __shfl_xor(pm, s);
      }
      if (l31 == 0) {
        const int idx = (row0 + rl) * NCH + bn;
        pdotg[idx] = pd; pesqg[idx] = pe; pmsqg[idx] = pq; pmsg[idx] = pm;
      }
    }
  }
}

// ---------------- Kernel 3: reduce partials -> sims, msum ----------------
__global__ __launch_bounds__(256) void finalize_k(
    const float* __restrict__ pd, const float* __restrict__ pe,
    const float* __restrict__ pq, const float* __restrict__ pm,
    float* __restrict__ sims, float* __restrict__ mst) {
  const int r = blockIdx.x * 256 + threadIdx.x;
  float d = 0.f, e = 0.f, q = 0.f, m = 0.f;
#pragma unroll
  for (int i = 0; i < NCH; ++i) {
    d += pd[r * NCH + i];
    e += pe[r * NCH + i];
    q += pq[r * NCH + i];
    m += pm[r * NCH + i];
  }
  sims[r] = -d / (sqrtf(fmaxf(e, 1e-12f)) * sqrtf(fmaxf(q, 1e-12f)));
  mst[r] = m;
}

// ------------- Kernel 4: softmax over B=8192 + final scaling -------------
__global__ __launch_bounds__(1024) void softmax_out_k(
    const float* __restrict__ sims, const float* __restrict__ mst,
    float* __restrict__ out) {
  __shared__ float red[16];
  const int t = threadIdx.x;
  float v[8];
  float mx = -1e30f;
#pragma unroll
  for (int i = 0; i < 8; ++i) {
    v[i] = sims[t + i * 1024];
    mx = fmaxf(mx, v[i]);
  }
#pragma unroll
  for (int s = 1; s < 64; s <<= 1) mx = fmaxf(mx, __shfl_xor(mx, s));
  if ((t & 63) == 0) red[t >> 6] = mx;
  __syncthreads();
  float m2 = red[0];
#pragma unroll
  for (int i = 1; i < 16; ++i) m2 = fmaxf(m2, red[i]);
  mx = m2;
  float sum = 0.f;
#pragma unroll
  for (int i = 0; i < 8; ++i) sum += __expf(v[i] - mx);
#pragma unroll
  for (int s = 1; s < 64; s <<= 1) sum += __shfl_xor(sum, s);
  __syncthreads();
  if ((t & 63) == 0) red[t >> 6] = sum;
  __syncthreads();
  float s2 = 0.f;
#pragma unroll
  for (int i = 0; i < 16; ++i) s2 += red[i];
  const float inv = 1.0f / s2;
#pragma unroll
  for (int i = 0; i < 8; ++i)
    out[t + i * 1024] = __expf(v[i] - mx) * inv * mst[t + i * 1024];
}

extern "C" void kernel_launch(void* const* d_in, const int* in_sizes, int n_in,
                              void* d_out, int out_size, void* d_ws, size_t ws_size,
                              hipStream_t stream) {
  const float* memry = (const float*)d_in[0];  // [B, M]
  const float* co    = (const float*)d_in[1];  // [B, C]
  const float* W     = (const float*)d_in[2];  // [C, M]
  const float* bvec  = (const float*)d_in[3];  // [M]
  float* out = (float*)d_out;                  // [B]

  char* w = (char*)d_ws;
  unsigned short* Wt  = (unsigned short*)w;                       // 8 MiB
  unsigned short* Abf = Wt + (size_t)NM * NC;                     // 16 MiB
  float* pdot = (float*)(Abf + (size_t)NB * NC);                  // 8192*16 f32 each
  float* pesq = pdot + (size_t)NB * NCH;
  float* pmsq = pesq + (size_t)NB * NCH;
  float* pms  = pmsq + (size_t)NB * NCH;
  float* sims = pms  + (size_t)NB * NCH;
  float* mst  = sims + NB;

  prep_k<<<1024 + (size_t)NB * NC / (256 * 8), 256, 0, stream>>>(W, Wt, co, Abf);
  gemm_fused<<<dim3(NB / 256, NM / 256), 512, 0, stream>>>(Abf, memry, Wt, bvec,
                                                           pdot, pesq, pmsq, pms);
  finalize_k<<<NB / 256, 256, 0, stream>>>(pdot, pesq, pmsq, pms, sims, mst);
  softmax_out_k<<<1, 1024, 0, stream>>>(sims, mst, out);
}

// Round 10
// 122.622 us; speedup vs baseline: 1.0839x; 1.0839x over previous
//
#include <hip/hip_runtime.h>

#define NB 8192   // batch
#define NC 1024   // controller width (K)
#define NM 4096   // memory size (N)
#define NCH 32    // NM / 128 (128-col chunks per row)

typedef __attribute__((ext_vector_type(8))) short bf16x8;
typedef __attribute__((ext_vector_type(4))) float f32x4;

__device__ __forceinline__ unsigned short f2bf(float x) {
  unsigned int u = __float_as_uint(x);
  u += 0x7FFFu + ((u >> 16) & 1u);
  return (unsigned short)(u >> 16);
}
__device__ __forceinline__ float bf2f(unsigned short h) {
  return __uint_as_float(((unsigned int)h) << 16);
}
__device__ __forceinline__ unsigned int pk2(float a, float b) {
  return (unsigned int)f2bf(a) | ((unsigned int)f2bf(b) << 16);
}

__device__ __forceinline__ void gload_lds16(const void* g, void* l) {
  __builtin_amdgcn_global_load_lds(
      (const __attribute__((address_space(1))) unsigned int*)g,
      (__attribute__((address_space(3))) unsigned int*)l, 16, 0, 0);
}

#define DSR(dst, addr, IMM) \
  asm volatile("ds_read_b128 %0, %1 offset:" IMM : "=v"(dst) : "v"(addr))

// ------- Kernel 0: fused prep: W [K,N] f32 -> Wt [N,K] bf16  AND co -> bf16 ----
__global__ __launch_bounds__(256) void prep_k(const float* __restrict__ W,
                                              unsigned short* __restrict__ Wt,
                                              const float* __restrict__ coin,
                                              unsigned short* __restrict__ Abf) {
  __shared__ float tile[64][65];
  const int bid = blockIdx.x;
  const int t = threadIdx.x;
  if (bid < 1024) {  // ---- convW part ----
    const int n0 = (bid & 63) * 64, k0 = (bid >> 6) * 64;
    const int r = t >> 2, q = t & 3;
    const float4* src = reinterpret_cast<const float4*>(W + (size_t)(k0 + r) * NM + n0 + q * 16);
    float4 x0 = src[0], x1 = src[1], x2 = src[2], x3 = src[3];
    float* tr = &tile[r][q * 16];
    tr[0]=x0.x; tr[1]=x0.y; tr[2]=x0.z;  tr[3]=x0.w;
    tr[4]=x1.x; tr[5]=x1.y; tr[6]=x1.z;  tr[7]=x1.w;
    tr[8]=x2.x; tr[9]=x2.y; tr[10]=x2.z; tr[11]=x2.w;
    tr[12]=x3.x; tr[13]=x3.y; tr[14]=x3.z; tr[15]=x3.w;
    __syncthreads();
    unsigned int pk[8];
#pragma unroll
    for (int i = 0; i < 8; ++i)
      pk[i] = pk2(tile[q * 16 + 2 * i][r], tile[q * 16 + 2 * i + 1][r]);
    int4* dst = reinterpret_cast<int4*>(Wt + (size_t)(n0 + r) * NC + k0 + q * 16);
    dst[0] = make_int4((int)pk[0], (int)pk[1], (int)pk[2], (int)pk[3]);
    dst[1] = make_int4((int)pk[4], (int)pk[5], (int)pk[6], (int)pk[7]);
  } else {  // ---- convA part ----
    const size_t i = ((size_t)(bid - 1024) * 256 + t) * 8;
    const float4* s = reinterpret_cast<const float4*>(coin + i);
    float4 x0 = s[0], x1 = s[1];
    int4 o = make_int4((int)pk2(x0.x, x0.y), (int)pk2(x0.z, x0.w),
                       (int)pk2(x1.x, x1.y), (int)pk2(x1.z, x1.w));
    *reinterpret_cast<int4*>(Abf + i) = o;
  }
}

// ------- Kernel 2: 256x128-tile bf16 MFMA GEMM, BK=32, 3-slot LDS rotation,
//         counted vmcnt(3), 2 blocks/CU (72 KiB LDS), 8 waves (4M x 2N)
//         + two-phase fused epilogue -------
// Slot layout (halfwords): A [256][32] at [0..8192), B [128][32] at [8192..12288).
// Phase p reads slot p%3, stages K-step p+2 into slot (p+2)%3 (WAR: that slot's
// last read was phase p-1, behind its closing barrier). VM3 per phase retires
// the stage issued at p-1 (= K-step p+1's data) -> counted vmcnt, never drain.
__global__ __launch_bounds__(512, 4) void gemm_fused(
    const unsigned short* __restrict__ Abf, const float* __restrict__ memry,
    const unsigned short* __restrict__ Wt, const float* __restrict__ bvec,
    float* __restrict__ pdotg, float* __restrict__ pesqg,
    float* __restrict__ pmsqg, float* __restrict__ pmsg) {
  __shared__ __align__(16) unsigned short LDS[3][12288];  // 72 KiB
  // XCD map: XCD x owns 4 B-panels (1 MB, L2-resident); bm sweeps inner.
  const int didx = blockIdx.y * 32 + blockIdx.x;
  const int xcd = didx & 7, s = didx >> 3;
  const int bm = s >> 2, bn = xcd * 4 + (s & 3);
  const int row0 = bm * 256, col0 = bn * 128;
  const int t = threadIdx.x;
  const int wid = t >> 6, lane = t & 63;
  const int wr = wid >> 1, wc = wid & 1;          // 4 x 2 waves
  const int l15 = lane & 15, lg = lane >> 4;
  const int ga8 = (lg ^ ((l15 >> 1) & 3)) * 8;    // swizzled k-granule (halfwords)

  f32x4 acc[4][4];
#pragma unroll
  for (int mi = 0; mi < 4; ++mi)
#pragma unroll
    for (int ni = 0; ni < 4; ++ni) acc[mi][ni] = (f32x4){0.f, 0.f, 0.f, 0.f};

  const unsigned ldsbase =
      (unsigned)(uintptr_t)(__attribute__((address_space(3))) void*)&LDS[0][0];
  const unsigned abase = ldsbase + ((wr * 64 + l15) * 32 + ga8) * 2;
  const unsigned bbase = ldsbase + 16384 + ((wc * 64 + l15) * 32 + ga8) * 2;

  // staging source (pre-swizzled column granule, rule #21)
  const int srow = t >> 2;                               // 0..127
  const int sk8 = ((t & 3) ^ ((srow >> 1) & 3)) * 8;
  const unsigned short* gA = Abf + (size_t)(row0 + srow) * NC + sk8;
  const unsigned short* gB = Wt + (size_t)(col0 + srow) * NC + sk8;

#define STG(SL, KT)                                                   \
  {                                                                   \
    gload_lds16(gA + (KT) * 32, &LDS[SL][t * 8]);                     \
    gload_lds16(gA + 128 * NC + (KT) * 32, &LDS[SL][4096 + t * 8]);   \
    gload_lds16(gB + (KT) * 32, &LDS[SL][8192 + t * 8]);              \
  }
#define NOSTG
#define VM3 asm volatile("s_waitcnt vmcnt(3)" ::: "memory")
#define VM0 asm volatile("s_waitcnt vmcnt(0)" ::: "memory")
#define NOVM

#define PH(SL, STAGE, VM)                                                    \
  {                                                                          \
    const unsigned ba = bbase + (SL)*24576;                                  \
    DSR(b[0], ba, "0");    DSR(b[1], ba, "1024");                            \
    DSR(b[2], ba, "2048"); DSR(b[3], ba, "3072");                            \
    const unsigned aa = abase + (SL)*24576;                                  \
    DSR(a[0], aa, "0");    DSR(a[1], aa, "1024");                            \
    DSR(a[2], aa, "2048"); DSR(a[3], aa, "3072");                            \
    STAGE;                                                                   \
    VM;                                                                      \
    __builtin_amdgcn_s_barrier();                                            \
    asm volatile("s_waitcnt lgkmcnt(0)" ::: "memory");                       \
    __builtin_amdgcn_sched_barrier(0);                                       \
    __builtin_amdgcn_s_setprio(1);                                           \
    _Pragma("unroll") for (int mi = 0; mi < 4; ++mi)                         \
        _Pragma("unroll") for (int ni = 0; ni < 4; ++ni)                     \
            acc[mi][ni] = __builtin_amdgcn_mfma_f32_16x16x32_bf16(           \
                a[mi], b[ni], acc[mi][ni], 0, 0, 0);                         \
    __builtin_amdgcn_s_setprio(0);                                           \
    __builtin_amdgcn_s_barrier();                                            \
    __builtin_amdgcn_sched_barrier(0);                                       \
  }

  // ---- prologue: K-steps 0,1 -> slots 0,1 (6 loads); VM3 -> K0 landed ----
  STG(0, 0);
  STG(1, 1);
  VM3;
  __builtin_amdgcn_s_barrier();
  __builtin_amdgcn_sched_barrier(0);

  bf16x8 a[4], b[4];
  // ---- main loop: 10 iterations x 3 phases (K-steps 0..29) ----
  for (int it = 0; it < 10; ++it) {
    const int k2 = 3 * it + 2, k3 = 3 * it + 3, k4 = 3 * it + 4;
    PH(0, STG(2, k2), VM3);
    PH(1, STG(0, k3), VM3);
    PH(2, STG(1, k4), VM3);
  }
  // ---- tail: K-steps 30 (slot 0), 31 (slot 1) ----
  PH(0, NOSTG, VM0);
  PH(1, NOSTG, NOVM);
#undef PH
#undef STG

  // ---- E1: e = exp(z + b) -> bf16 into LDS [256][128] (64 KiB, fits 72) ----
  unsigned short (*e_lds)[128] = reinterpret_cast<unsigned short(*)[128]>(&LDS[0][0]);
  float bv[4];
#pragma unroll
  for (int ni = 0; ni < 4; ++ni) bv[ni] = bvec[col0 + wc * 64 + ni * 16 + l15];
#pragma unroll
  for (int mi = 0; mi < 4; ++mi)
#pragma unroll
    for (int ni = 0; ni < 4; ++ni)
#pragma unroll
      for (int j = 0; j < 4; ++j) {
        const int rl = wr * 64 + mi * 16 + 4 * lg + j;
        const int cl = wc * 64 + ni * 16 + l15;
        e_lds[rl][cl ^ (((rl >> 2) & 3) << 4)] = f2bf(__expf(acc[mi][ni][j] + bv[ni]));
      }
  __syncthreads();

  // ---- E2: coalesced fused pass: per row, partials of e*m, e^2, m^2, m ----
  {
    const int halfl = lane >> 5, l31 = lane & 31;
    const int rbase = wid * 32;  // each wave owns 32 consecutive rows
#pragma unroll 8
    for (int i = 0; i < 16; ++i) {
      const int rl = rbase + 2 * i + halfl;
      float4 m0 = *reinterpret_cast<const float4*>(
          memry + (size_t)(row0 + rl) * NM + col0 + l31 * 4);
      const int ec = (l31 * 4) ^ (((rl >> 2) & 3) << 4);
      unsigned long long ev = *reinterpret_cast<const unsigned long long*>(&e_lds[rl][ec]);
      float e0 = bf2f((unsigned short)(ev)),
            e1 = bf2f((unsigned short)(ev >> 16)),
            e2 = bf2f((unsigned short)(ev >> 32)),
            e3 = bf2f((unsigned short)(ev >> 48));
      float pd = e0 * m0.x + e1 * m0.y + e2 * m0.z + e3 * m0.w;
      float pe = e0 * e0 + e1 * e1 + e2 * e2 + e3 * e3;
      float pq = m0.x * m0.x + m0.y * m0.y + m0.z * m0.z + m0.w * m0.w;
      float pm = m0.x + m0.y + m0.z + m0.w;
#pragma unroll
      for (int sh = 1; sh < 32; sh <<= 1) {
        pd += __shfl_xor(pd, sh); pe += __shfl_xor(pe, sh);
        pq += __shfl_xor(pq, sh); pm += __shfl_xor(pm, sh);
      }
      if (l31 == 0) {
        const int idx = (row0 + rl) * NCH + bn;
        pdotg[idx] = pd; pesqg[idx] = pe; pmsqg[idx] = pq; pmsg[idx] = pm;
      }
    }
  }
}

// ---------------- Kernel 3: reduce partials -> sims, msum ----------------
__global__ __launch_bounds__(256) void finalize_k(
    const float* __restrict__ pd, const float* __restrict__ pe,
    const float* __restrict__ pq, const float* __restrict__ pm,
    float* __restrict__ sims, float* __restrict__ mst) {
  const int r = blockIdx.x * 256 + threadIdx.x;
  float d = 0.f, e = 0.f, q = 0.f, m = 0.f;
#pragma unroll
  for (int i = 0; i < NCH; ++i) {
    d += pd[r * NCH + i];
    e += pe[r * NCH + i];
    q += pq[r * NCH + i];
    m += pm[r * NCH + i];
  }
  sims[r] = -d / (sqrtf(fmaxf(e, 1e-12f)) * sqrtf(fmaxf(q, 1e-12f)));
  mst[r] = m;
}

// ------------- Kernel 4: softmax over B=8192 + final scaling -------------
__global__ __launch_bounds__(1024) void softmax_out_k(
    const float* __restrict__ sims, const float* __restrict__ mst,
    float* __restrict__ out) {
  __shared__ float red[16];
  const int t = threadIdx.x;
  float v[8];
  float mx = -1e30f;
#pragma unroll
  for (int i = 0; i < 8; ++i) {
    v[i] = sims[t + i * 1024];
    mx = fmaxf(mx, v[i]);
  }
#pragma unroll
  for (int s = 1; s < 64; s <<= 1) mx = fmaxf(mx, __shfl_xor(mx, s));
  if ((t & 63) == 0) red[t >> 6] = mx;
  __syncthreads();
  float m2 = red[0];
#pragma unroll
  for (int i = 1; i < 16; ++i) m2 = fmaxf(m2, red[i]);
  mx = m2;
  float sum = 0.f;
#pragma unroll
  for (int i = 0; i < 8; ++i) sum += __expf(v[i] - mx);
#pragma unroll
  for (int s = 1; s < 64; s <<= 1) sum += __shfl_xor(sum, s);
  __syncthreads();
  if ((t & 63) == 0) red[t >> 6] = sum;
  __syncthreads();
  float s2 = 0.f;
#pragma unroll
  for (int i = 0; i < 16; ++i) s2 += red[i];
  const float inv = 1.0f / s2;
#pragma unroll
  for (int i = 0; i < 8; ++i)
    out[t + i * 1024] = __expf(v[i] - mx) * inv * mst[t + i * 1024];
}

extern "C" void kernel_launch(void* const* d_in, const int* in_sizes, int n_in,
                              void* d_out, int out_size, void* d_ws, size_t ws_size,
                              hipStream_t stream) {
  const float* memry = (const float*)d_in[0];  // [B, M]
  const float* co    = (const float*)d_in[1];  // [B, C]
  const float* W     = (const float*)d_in[2];  // [C, M]
  const float* bvec  = (const float*)d_in[3];  // [M]
  float* out = (float*)d_out;                  // [B]

  char* w = (char*)d_ws;
  unsigned short* Wt  = (unsigned short*)w;                       // 8 MiB
  unsigned short* Abf = Wt + (size_t)NM * NC;                     // 16 MiB
  float* pdot = (float*)(Abf + (size_t)NB * NC);                  // 8192*32 f32 each
  float* pesq = pdot + (size_t)NB * NCH;
  float* pmsq = pesq + (size_t)NB * NCH;
  float* pms  = pmsq + (size_t)NB * NCH;
  float* sims = pms  + (size_t)NB * NCH;
  float* mst  = sims + NB;

  prep_k<<<1024 + (size_t)NB * NC / (256 * 8), 256, 0, stream>>>(W, Wt, co, Abf);
  gemm_fused<<<dim3(32, 32), 512, 0, stream>>>(Abf, memry, Wt, bvec,
                                               pdot, pesq, pmsq, pms);
  finalize_k<<<NB / 256, 256, 0, stream>>>(pdot, pesq, pmsq, pms, sims, mst);
  softmax_out_k<<<1, 1024, 0, stream>>>(sims, mst, out);
}

// Round 11
// 107.423 us; speedup vs baseline: 1.2372x; 1.1415x over previous
//
#include <hip/hip_runtime.h>

#define NB 8192   // batch
#define NC 1024   // controller width (K)
#define NM 4096   // memory size (N)
#define NCH 16    // NM / 256 (256-col chunks per row)

typedef __attribute__((ext_vector_type(8))) short bf16x8;
typedef __attribute__((ext_vector_type(4))) float f32x4;

__device__ __forceinline__ unsigned short f2bf(float x) {
  unsigned int u = __float_as_uint(x);
  u += 0x7FFFu + ((u >> 16) & 1u);
  return (unsigned short)(u >> 16);
}
__device__ __forceinline__ float bf2f(unsigned short h) {
  return __uint_as_float(((unsigned int)h) << 16);
}
__device__ __forceinline__ unsigned int pk2(float a, float b) {
  return (unsigned int)f2bf(a) | ((unsigned int)f2bf(b) << 16);
}

__device__ __forceinline__ void gload_lds16(const void* g, void* l) {
  __builtin_amdgcn_global_load_lds(
      (const __attribute__((address_space(1))) unsigned int*)g,
      (__attribute__((address_space(3))) unsigned int*)l, 16, 0, 0);
}

#define DSR(dst, addr, IMM) \
  asm volatile("ds_read_b128 %0, %1 offset:" IMM : "=v"(dst) : "v"(addr))

// ------- Kernel 0: fused prep: W [K,N] f32 -> Wt [N,K] bf16  AND co -> bf16 ----
__global__ __launch_bounds__(256) void prep_k(const float* __restrict__ W,
                                              unsigned short* __restrict__ Wt,
                                              const float* __restrict__ coin,
                                              unsigned short* __restrict__ Abf) {
  __shared__ float tile[64][65];
  const int bid = blockIdx.x;
  const int t = threadIdx.x;
  if (bid < 1024) {  // ---- convW part ----
    const int n0 = (bid & 63) * 64, k0 = (bid >> 6) * 64;
    const int r = t >> 2, q = t & 3;
    const float4* src = reinterpret_cast<const float4*>(W + (size_t)(k0 + r) * NM + n0 + q * 16);
    float4 x0 = src[0], x1 = src[1], x2 = src[2], x3 = src[3];
    float* tr = &tile[r][q * 16];
    tr[0]=x0.x; tr[1]=x0.y; tr[2]=x0.z;  tr[3]=x0.w;
    tr[4]=x1.x; tr[5]=x1.y; tr[6]=x1.z;  tr[7]=x1.w;
    tr[8]=x2.x; tr[9]=x2.y; tr[10]=x2.z; tr[11]=x2.w;
    tr[12]=x3.x; tr[13]=x3.y; tr[14]=x3.z; tr[15]=x3.w;
    __syncthreads();
    unsigned int pk[8];
#pragma unroll
    for (int i = 0; i < 8; ++i)
      pk[i] = pk2(tile[q * 16 + 2 * i][r], tile[q * 16 + 2 * i + 1][r]);
    int4* dst = reinterpret_cast<int4*>(Wt + (size_t)(n0 + r) * NC + k0 + q * 16);
    dst[0] = make_int4((int)pk[0], (int)pk[1], (int)pk[2], (int)pk[3]);
    dst[1] = make_int4((int)pk[4], (int)pk[5], (int)pk[6], (int)pk[7]);
  } else {  // ---- convA part ----
    const size_t i = ((size_t)(bid - 1024) * 256 + t) * 8;
    const float4* s = reinterpret_cast<const float4*>(coin + i);
    float4 x0 = s[0], x1 = s[1];
    int4 o = make_int4((int)pk2(x0.x, x0.y), (int)pk2(x0.z, x0.w),
                       (int)pk2(x1.x, x1.y), (int)pk2(x1.z, x1.w));
    *reinterpret_cast<int4*>(Abf + i) = o;
  }
}

// ------- Kernel 2: 256x256-tile 8-phase bf16 MFMA GEMM with FRAGMENT
//         REGISTER DOUBLE-BUFFERING (reads for phase p+1 overlap MFMA of p,
//         counted lgkmcnt) + two-phase fused epilogue -------
// LDS[slot][type][8192 hw]: type 0=Ak0 1=Ak1 2=Bk0 3=Bk1. Stage: linear dest,
// pre-swizzled global source kg=(t&3)^((t>>3)&3); reads apply same XOR.
// Hazards: WAR covered by per-phase closing barriers; RAW stage->read covered
// by VM8 one phase before the read (barrier between vmcnt and cross-wave read).
__global__ __launch_bounds__(512) void gemm_fused(
    const unsigned short* __restrict__ Abf, const float* __restrict__ memry,
    const unsigned short* __restrict__ Wt, const float* __restrict__ bvec,
    float* __restrict__ pdotg, float* __restrict__ pesqg,
    float* __restrict__ pmsqg, float* __restrict__ pmsg) {
  __shared__ __align__(16) unsigned short LDS[2][4][8192];  // 128 KiB
  const int bm = blockIdx.x, bn = blockIdx.y;
  const int row0 = bm * 256, col0 = bn * 256;
  const int t = threadIdx.x;
  const int wid = t >> 6, lane = t & 63;
  const int wr = wid >> 2, wc = wid & 3;          // 2 x 4 waves
  const int l15 = lane & 15, lg = lane >> 4;
  const int ga8 = (lg ^ ((l15 >> 1) & 3)) * 8;    // swizzled k-granule (halfwords)

  f32x4 acc[8][4];
#pragma unroll
  for (int mi = 0; mi < 8; ++mi)
#pragma unroll
    for (int ni = 0; ni < 4; ++ni) acc[mi][ni] = (f32x4){0.f, 0.f, 0.f, 0.f};

  const unsigned ldsbase =
      (unsigned)(uintptr_t)(__attribute__((address_space(3))) void*)&LDS[0][0][0];
  const unsigned abase = ldsbase + ((wr * 128 + l15) * 32 + ga8) * 2;
  const unsigned bbase = ldsbase + 32768 + ((wc * 64 + l15) * 32 + ga8) * 2;

  const int srow0 = t >> 2;
  const int sk8 = ((t & 3) ^ ((srow0 >> 1) & 3)) * 8;
  const unsigned short* gA = Abf + (size_t)(row0 + srow0) * NC + sk8;
  const unsigned short* gB = Wt + (size_t)(col0 + srow0) * NC + sk8;

#define STG(SL, TY, KT)                                                      \
  {                                                                          \
    const unsigned short* s0 = ((TY) <= 1 ? gA : gB) + (KT) * 64 + ((TY)&1) * 32; \
    gload_lds16(s0, &LDS[SL][TY][t * 8]);                                    \
    gload_lds16(s0 + (size_t)128 * NC, &LDS[SL][TY][t * 8 + 4096]);          \
  }
#define NOSTG
#define VM10 asm volatile("s_waitcnt vmcnt(10)" ::: "memory")
#define VM8 asm volatile("s_waitcnt vmcnt(8)" ::: "memory")
#define VM4 asm volatile("s_waitcnt vmcnt(4)" ::: "memory")
#define VM0 asm volatile("s_waitcnt vmcnt(0)" ::: "memory")
#define NOVM

  // phase p: [ds_reads for p+1 into LD-banks] [stage] [vm] [barrier]
  //          [lgkmcnt(#reads issued this phase)] [MFMA on banks read at p-1]
  //          [barrier]
#define PH(ACCH, AMF, BMF, LDB, BLD, LDA, ALD, NSL, NS, NMH, STAGE, VM, LGK) \
  {                                                                          \
    if (LDB) {                                                               \
      const unsigned ba = bbase + (NSL)*65536 + (NS)*16384;                  \
      DSR(BLD[0], ba, "0");    DSR(BLD[1], ba, "1024");                      \
      DSR(BLD[2], ba, "2048"); DSR(BLD[3], ba, "3072");                      \
    }                                                                        \
    if (LDA) {                                                               \
      const unsigned aa = abase + (NSL)*65536 + (NS)*16384 + (NMH)*4096;     \
      DSR(ALD[0], aa, "0");    DSR(ALD[1], aa, "1024");                      \
      DSR(ALD[2], aa, "2048"); DSR(ALD[3], aa, "3072");                      \
    }                                                                        \
    STAGE;                                                                   \
    VM;                                                                      \
    __builtin_amdgcn_s_barrier();                                            \
    asm volatile("s_waitcnt lgkmcnt(" LGK ")" ::: "memory");                 \
    __builtin_amdgcn_sched_barrier(0);                                       \
    __builtin_amdgcn_s_setprio(1);                                           \
    _Pragma("unroll") for (int mi = 0; mi < 4; ++mi)                         \
        _Pragma("unroll") for (int ni = 0; ni < 4; ++ni)                     \
            acc[(ACCH)*4 + mi][ni] = __builtin_amdgcn_mfma_f32_16x16x32_bf16(\
                AMF[mi], BMF[ni], acc[(ACCH)*4 + mi][ni], 0, 0, 0);          \
    __builtin_amdgcn_s_setprio(0);                                           \
    __builtin_amdgcn_s_barrier();                                            \
    __builtin_amdgcn_sched_barrier(0);                                       \
  }

  // ---- prologue: slot0 (K-tile 0) + slot1 minus Ak1 (K-tile 1) ----
  STG(0, 2, 0); STG(0, 0, 0); STG(0, 3, 0); STG(0, 1, 0);
  STG(1, 2, 1); STG(1, 0, 1); STG(1, 3, 1);
  VM10;  // retire first 2 STGs (slot0 B-k0, A-k0)
  __builtin_amdgcn_s_barrier();
  __builtin_amdgcn_sched_barrier(0);

  bf16x8 aA[4], aB[4], bA[4], bB[4];
  // fragments for t1: B from LDS[0][2], A from LDS[0][0] MH0
  {
    const unsigned ba = bbase;
    DSR(bA[0], ba, "0");    DSR(bA[1], ba, "1024");
    DSR(bA[2], ba, "2048"); DSR(bA[3], ba, "3072");
    const unsigned aa = abase;
    DSR(aA[0], aa, "0");    DSR(aA[1], aa, "1024");
    DSR(aA[2], aa, "2048"); DSR(aA[3], aa, "3072");
  }

  // ---- main loop: 7 iterations x 2 K-tiles ----
  for (int it = 0; it < 7; ++it) {
    const int c1 = 2 * it + 1, c2 = 2 * it + 2, c3 = 2 * it + 3;
    PH(0, aA, bA, 0, bB, 1, aB, 0, 0, 1, STG(1, 1, c1), VM8,  "4");  // t1
    PH(1, aB, bA, 1, bB, 1, aA, 0, 1, 0, STG(0, 2, c2), NOVM, "8");  // t2
    PH(0, aA, bB, 0, bA, 1, aB, 0, 1, 1, STG(0, 0, c2), VM8,  "4");  // t3
    PH(1, aB, bB, 1, bA, 1, aA, 1, 0, 0, STG(0, 3, c2), NOVM, "8");  // t4
    PH(0, aA, bA, 0, bB, 1, aB, 1, 0, 1, STG(0, 1, c2), VM8,  "4");  // t5
    PH(1, aB, bA, 1, bB, 1, aA, 1, 1, 0, STG(1, 2, c3), NOVM, "8");  // t6
    PH(0, aA, bB, 0, bA, 1, aB, 1, 1, 1, STG(1, 0, c3), VM8,  "4");  // t7
    PH(1, aB, bB, 1, bA, 1, aA, 0, 0, 0, STG(1, 3, c3), NOVM, "8");  // t8
  }
  // ---- final iteration (K-tiles 14, 15): drain vmcnt VM8 -> VM4 -> VM0 ----
  PH(0, aA, bA, 0, bB, 1, aB, 0, 0, 1, STG(1, 1, 15), VM8,  "4");  // f1
  PH(1, aB, bA, 1, bB, 1, aA, 0, 1, 0, NOSTG,         NOVM, "8");  // f2
  PH(0, aA, bB, 0, bA, 1, aB, 0, 1, 1, NOSTG,         VM4,  "4");  // f3
  PH(1, aB, bB, 1, bA, 1, aA, 1, 0, 0, NOSTG,         NOVM, "8");  // f4
  PH(0, aA, bA, 0, bB, 1, aB, 1, 0, 1, NOSTG,         VM0,  "4");  // f5
  PH(1, aB, bA, 1, bB, 1, aA, 1, 1, 0, NOSTG,         NOVM, "8");  // f6
  PH(0, aA, bB, 0, bA, 1, aB, 1, 1, 1, NOSTG,         NOVM, "4");  // f7
  PH(1, aB, bB, 0, bA, 0, aA, 0, 0, 0, NOSTG,         NOVM, "0");  // f8
#undef PH
#undef STG

  // ---- E1: e = exp(z + b) -> bf16 into LDS [256][256], col-XOR banks ----
  unsigned short (*e_lds)[256] = reinterpret_cast<unsigned short(*)[256]>(&LDS[0][0][0]);
  float bv[4];
#pragma unroll
  for (int ni = 0; ni < 4; ++ni) bv[ni] = bvec[col0 + wc * 64 + ni * 16 + l15];
#pragma unroll
  for (int mi = 0; mi < 8; ++mi)
#pragma unroll
    for (int ni = 0; ni < 4; ++ni)
#pragma unroll
      for (int j = 0; j < 4; ++j) {
        const int rl = wr * 128 + mi * 16 + 4 * lg + j;
        const int cl = wc * 64 + ni * 16 + l15;
        e_lds[rl][cl ^ (((rl >> 2) & 3) << 4)] = f2bf(__expf(acc[mi][ni][j] + bv[ni]));
      }
  __syncthreads();

  // ---- E2: coalesced fused pass: per row, partials of e*m, e^2, m^2, m ----
  {
    const int halfl = lane >> 5, l31 = lane & 31;
    const int rbase = wid * 32;  // each wave owns 32 consecutive rows
#pragma unroll 8
    for (int i = 0; i < 16; ++i) {
      const int rl = rbase + 2 * i + halfl;
      const float4* mp = reinterpret_cast<const float4*>(
          memry + (size_t)(row0 + rl) * NM + col0 + l31 * 8);
      float4 m0 = mp[0], m1 = mp[1];
      bf16x8 ev = *reinterpret_cast<const bf16x8*>(
          &e_lds[rl][(l31 * 8) ^ (((rl >> 2) & 3) << 4)]);
      float mv[8] = {m0.x, m0.y, m0.z, m0.w, m1.x, m1.y, m1.z, m1.w};
      float pd = 0.f, pe = 0.f, pq = 0.f, pm = 0.f;
#pragma unroll
      for (int k = 0; k < 8; ++k) {
        float e = bf2f((unsigned short)ev[k]);
        pd += e * mv[k]; pe += e * e; pq += mv[k] * mv[k]; pm += mv[k];
      }
#pragma unroll
      for (int s = 1; s < 32; s <<= 1) {
        pd += __shfl_xor(pd, s); pe += __shfl_xor(pe, s);
        pq += __shfl_xor(pq, s); pm += __shfl_xor(pm, s);
      }
      if (l31 == 0) {
        const int idx = (row0 + rl) * NCH + bn;
        pdotg[idx] = pd; pesqg[idx] = pe; pmsqg[idx] = pq; pmsg[idx] = pm;
      }
    }
  }
}

// ---------------- Kernel 3: reduce partials -> sims, msum ----------------
__global__ __launch_bounds__(256) void finalize_k(
    const float* __restrict__ pd, const float* __restrict__ pe,
    const float* __restrict__ pq, const float* __restrict__ pm,
    float* __restrict__ sims, float* __restrict__ mst) {
  const int r = blockIdx.x * 256 + threadIdx.x;
  float d = 0.f, e = 0.f, q = 0.f, m = 0.f;
#pragma unroll
  for (int i = 0; i < NCH; ++i) {
    d += pd[r * NCH + i];
    e += pe[r * NCH + i];
    q += pq[r * NCH + i];
    m += pm[r * NCH + i];
  }
  sims[r] = -d / (sqrtf(fmaxf(e, 1e-12f)) * sqrtf(fmaxf(q, 1e-12f)));
  mst[r] = m;
}

// ------------- Kernel 4: softmax over B=8192 + final scaling -------------
__global__ __launch_bounds__(1024) void softmax_out_k(
    const float* __restrict__ sims, const float* __restrict__ mst,
    float* __restrict__ out) {
  __shared__ float red[16];
  const int t = threadIdx.x;
  float v[8];
  float mx = -1e30f;
#pragma unroll
  for (int i = 0; i < 8; ++i) {
    v[i] = sims[t + i * 1024];
    mx = fmaxf(mx, v[i]);
  }
#pragma unroll
  for (int s = 1; s < 64; s <<= 1) mx = fmaxf(mx, __shfl_xor(mx, s));
  if ((t & 63) == 0) red[t >> 6] = mx;
  __syncthreads();
  float m2 = red[0];
#pragma unroll
  for (int i = 1; i < 16; ++i) m2 = fmaxf(m2, red[i]);
  mx = m2;
  float sum = 0.f;
#pragma unroll
  for (int i = 0; i < 8; ++i) sum += __expf(v[i] - mx);
#pragma unroll
  for (int s = 1; s < 64; s <<= 1) sum += __shfl_xor(sum, s);
  __syncthreads();
  if ((t & 63) == 0) red[t >> 6] = sum;
  __syncthreads();
  float s2 = 0.f;
#pragma unroll
  for (int i = 0; i < 16; ++i) s2 += red[i];
  const float inv = 1.0f / s2;
#pragma unroll
  for (int i = 0; i < 8; ++i)
    out[t + i * 1024] = __expf(v[i] - mx) * inv * mst[t + i * 1024];
}

extern "C" void kernel_launch(void* const* d_in, const int* in_sizes, int n_in,
                              void* d_out, int out_size, void* d_ws, size_t ws_size,
                              hipStream_t stream) {
  const float* memry = (const float*)d_in[0];  // [B, M]
  const float* co    = (const float*)d_in[1];  // [B, C]
  const float* W     = (const float*)d_in[2];  // [C, M]
  const float* bvec  = (const float*)d_in[3];  // [M]
  float* out = (float*)d_out;                  // [B]

  char* w = (char*)d_ws;
  unsigned short* Wt  = (unsigned short*)w;                       // 8 MiB
  unsigned short* Abf = Wt + (size_t)NM * NC;                     // 16 MiB
  float* pdot = (float*)(Abf + (size_t)NB * NC);                  // 8192*16 f32 each
  float* pesq = pdot + (size_t)NB * NCH;
  float* pmsq = pesq + (size_t)NB * NCH;
  float* pms  = pmsq + (size_t)NB * NCH;
  float* sims = pms  + (size_t)NB * NCH;
  float* mst  = sims + NB;

  prep_k<<<1024 + (size_t)NB * NC / (256 * 8), 256, 0, stream>>>(W, Wt, co, Abf);
  gemm_fused<<<dim3(NB / 256, NM / 256), 512, 0, stream>>>(Abf, memry, Wt, bvec,
                                                           pdot, pesq, pmsq, pms);
  finalize_k<<<NB / 256, 256, 0, stream>>>(pdot, pesq, pmsq, pms, sims, mst);
  softmax_out_k<<<1, 1024, 0, stream>>>(sims, mst, out);
}